// Round 5
// baseline (345.767 us; speedup 1.0000x reference)
//
#include <hip/hip_runtime.h>
#include <math.h>
#include <float.h>

#define B_ 64
#define S_ 512
#define N_ 256
#define P_ 96
#define D_ 64
#define WIN_ 24
#define L_ 488   // S_ - WIN_
#define MID_ 7
#define PB_ (P_*B_)   // 6144

// workspace layout (in floats)
#define OFF_XS   ((size_t)0)                        // season [B][L][N]
#define OFF_TRT  (OFF_XS  + (size_t)B_*L_*N_)       // trend^T [N][B][L]
#define OFF_ET   (OFF_TRT + (size_t)N_*B_*L_)       // embed_t [B][L][D]
#define OFF_EN   (OFF_ET  + (size_t)B_*L_*D_)       // embed_next [B][P][D]
#define OFF_WSE  (OFF_EN  + (size_t)B_*P_*D_)       // season weights [B][P][L]
#define OFF_WM   (OFF_WSE + (size_t)B_*P_*L_)       // mid weights [B][MID][L]
// trend-GEMM partials alias WSE (N*PB = 1.57M floats < 3.0M), consumed by
// k_reduce_trend BEFORE season scores write WSE.
#define OFF_PART OFF_WSE

// ---------------- Kernel 1: rolling-mean trend + season ----------------
// grid (B, 8), block 256 (thread = n). LDS-transposed trT writes.
__global__ __launch_bounds__(256) void k_trend(const float* __restrict__ X,
                                               float* __restrict__ ws) {
    int b = blockIdx.x, tile = blockIdx.y, n = threadIdx.x;
    __shared__ float tr_tile[256][61];   // stride 61 (odd): 2-way bank alias = free
    float* Xs  = ws + OFF_XS;
    float* trT = ws + OFF_TRT;
    const float* Xb = X + (size_t)b * S_ * N_ + n;
    int s1 = WIN_ + tile * 61;
    float wsum = 0.f;
    for (int s = s1 - WIN_; s < s1; ++s) wsum += Xb[(size_t)s * N_];
    for (int i = 0; i < 61; ++i) {
        int s = s1 + i, l = s - WIN_;
        float xv = Xb[(size_t)s * N_];
        wsum += xv - Xb[(size_t)(s - WIN_) * N_];
        float tr = wsum * (1.f / WIN_);
        Xs[((size_t)b * L_ + l) * N_ + n] = xv - tr;   // coalesced
        tr_tile[n][i] = tr;
    }
    __syncthreads();
    int lane = threadIdx.x & 63, row4 = threadIdx.x >> 6;
    int l0 = tile * 61;
    for (int r = row4; r < 256; r += 4) {
        if (lane < 61)
            trT[(size_t)r * (B_ * L_) + (size_t)b * L_ + l0 + lane] = tr_tile[r][lane];
    }
}

// ---------------- Kernel 2: time2vec embeds ----------------
__global__ __launch_bounds__(256) void k_embed(const float* __restrict__ T,
                                               const float* __restrict__ w0,
                                               const float* __restrict__ b0,
                                               const float* __restrict__ Wp,
                                               const float* __restrict__ Bp,
                                               float* __restrict__ ws) {
    int idx = blockIdx.x * 256 + threadIdx.x;
    int d = idx & 63;
    int rest = idx >> 6;
    int pos = rest % (L_ + P_);
    int b = rest / (L_ + P_);
    float t;
    float* dst;
    if (pos < L_) {
        t = T[(size_t)b * S_ + WIN_ + pos];
        dst = ws + OFF_ET + ((size_t)b * L_ + pos) * D_ + d;
    } else {
        int p = pos - L_;
        t = T[(size_t)b * S_ + (S_ - 1)] + (float)(p + 1);
        dst = ws + OFF_EN + ((size_t)b * P_ + p) * D_ + d;
    }
    float v = (d == 0) ? (t * w0[0] + b0[0]) : sinf(t * Wp[d - 1] + Bp[d - 1]);
    *dst = v;
}

// ------- Kernel 3: trend GEMM — W streamed per-thread from global, ---------
// trT chunk in LDS (k-major). grid (N_, 2 b-halves), block 256.
// thread (pt,btl): p = pt+16j (j<6), b_local = btl*2+i (i<2).
__global__ __launch_bounds__(256, 2) void k_trend_gemm(const float* __restrict__ Wt_g,
                                                       const float* __restrict__ ws_c,
                                                       float* __restrict__ part) {
    int n = blockIdx.x, bh = blockIdx.y, tid = threadIdx.x;
    __shared__ float smem[3072];          // Bl[32 k][34] = 1088 in loop; Cst 3072 at end
    float* Bl = smem;
    const float* trT = ws_c + OFF_TRT + (size_t)n * (B_ * L_) + (size_t)bh * 32 * L_;
    const float* Wn  = Wt_g + (size_t)n * P_ * L_;
    int pt = tid >> 4, btl = tid & 15;
    const float* wrow[6];
#pragma unroll
    for (int j = 0; j < 6; ++j) wrow[j] = Wn + (size_t)(pt + 16 * j) * L_;
    float acc[6][2] = {};
    float4 br;
    int frow = tid >> 3, fl4 = (tid & 7) * 4;

    auto fetchB = [&](int l0) {
        int cur = L_ - l0;
        br = (fl4 < cur) ? *(const float4*)&trT[(size_t)frow * L_ + l0 + fl4]
                         : make_float4(0.f, 0.f, 0.f, 0.f);
    };
    auto stageB = [&]() {                 // transpose to k-major
        Bl[(fl4 + 0) * 34 + frow] = br.x;
        Bl[(fl4 + 1) * 34 + frow] = br.y;
        Bl[(fl4 + 2) * 34 + frow] = br.z;
        Bl[(fl4 + 3) * 34 + frow] = br.w;
    };
    auto computeC = [&](int l0, int nk) {
#pragma unroll
        for (int lc = 0; lc < nk; lc += 4) {
            float4 wv[6];
#pragma unroll
            for (int j = 0; j < 6; ++j) wv[j] = *(const float4*)&wrow[j][l0 + lc];
            float2 bv[4];
#pragma unroll
            for (int t = 0; t < 4; ++t) bv[t] = *(const float2*)&Bl[(lc + t) * 34 + btl * 2];
#pragma unroll
            for (int t = 0; t < 4; ++t) {
#pragma unroll
                for (int j = 0; j < 6; ++j) {
                    float w = (t == 0) ? wv[j].x : (t == 1) ? wv[j].y : (t == 2) ? wv[j].z : wv[j].w;
                    acc[j][0] += w * bv[t].x;
                    acc[j][1] += w * bv[t].y;
                }
            }
        }
    };

    fetchB(0); stageB();
    for (int c = 1; c < 16; ++c) {        // chunks: 15x32 + tail 8
        fetchB(c * 32);
        __syncthreads();
        computeC((c - 1) * 32, 32);
        __syncthreads();
        stageB();
    }
    __syncthreads();
    computeC(480, 8);

    __syncthreads();                      // reuse smem as Cst[96][32]
    float* Cst = smem;
#pragma unroll
    for (int j = 0; j < 6; ++j) {
        Cst[(pt + 16 * j) * 32 + btl * 2 + 0] = acc[j][0];
        Cst[(pt + 16 * j) * 32 + btl * 2 + 1] = acc[j][1];
    }
    __syncthreads();
    float* dstp = part + (size_t)n * PB_ + (size_t)bh * 32;
    for (int idx = tid; idx < 768; idx += 256) {
        int p = idx >> 3, bl4 = (idx & 7) * 4;
        *(float4*)&dstp[(size_t)p * B_ + bl4] = *(const float4*)&Cst[p * 32 + bl4];
    }
}

// ------- Kernel 4: transpose partial[n][p][b] + bias -> out0 [b][p][n] -----
__global__ __launch_bounds__(256) void k_reduce_trend(const float* __restrict__ part,
                                                      const float* __restrict__ bt,
                                                      float* __restrict__ out0) {
    int nt = blockIdx.x, p = blockIdx.y, tid = threadIdx.x;
    __shared__ float t[32][65];
    int n0 = nt * 32;
    for (int idx = tid; idx < 2048; idx += 256) {
        int i = idx >> 6, j = idx & 63;
        t[i][j] = part[(size_t)(n0 + i) * PB_ + p * 64 + j];
    }
    __syncthreads();
    for (int idx = tid; idx < 2048; idx += 256) {
        int bb = idx >> 5, nl = idx & 31;
        out0[((size_t)bb * P_ + p) * N_ + n0 + nl] = t[nl][bb] + bt[(size_t)p * N_ + n0 + nl];
    }
}

// ------- Kernel 5: season scores — EN streamed per-thread, ET in LDS -------
// grid (B, 16 k-tiles of 32), block 256. thread: q = pt+16j, k = k0+ktl*2+i.
__global__ __launch_bounds__(256) void k_season_scores(float* __restrict__ ws) {
    int b = blockIdx.x, kt = blockIdx.y, tid = threadIdx.x;
    const float* EN = ws + OFF_EN + (size_t)b * P_ * D_;
    const float* ET = ws + OFF_ET + (size_t)b * L_ * D_;
    float* W = ws + OFF_WSE + (size_t)b * P_ * L_;
    __shared__ float El[64 * 34];         // [d][k-local 32], pad 34
    int k0 = kt * 32;
    for (int idx = tid; idx < 512; idx += 256) {
        int kk = idx >> 4, d4 = (idx & 15) * 4;
        float4 v = (k0 + kk < L_) ? *(const float4*)&ET[(size_t)(k0 + kk) * D_ + d4]
                                  : make_float4(0.f, 0.f, 0.f, 0.f);
        El[(d4 + 0) * 34 + kk] = v.x;
        El[(d4 + 1) * 34 + kk] = v.y;
        El[(d4 + 2) * 34 + kk] = v.z;
        El[(d4 + 3) * 34 + kk] = v.w;
    }
    __syncthreads();
    int pt = tid >> 4, ktl = tid & 15;
    const float* erow[6];
#pragma unroll
    for (int j = 0; j < 6; ++j) erow[j] = EN + (size_t)(pt + 16 * j) * D_;
    float acc[6][2] = {};
#pragma unroll
    for (int d = 0; d < 64; d += 4) {
        float4 wv[6];
#pragma unroll
        for (int j = 0; j < 6; ++j) wv[j] = *(const float4*)&erow[j][d];
        float2 bv[4];
#pragma unroll
        for (int m = 0; m < 4; ++m) bv[m] = *(const float2*)&El[(d + m) * 34 + ktl * 2];
#pragma unroll
        for (int m = 0; m < 4; ++m) {
#pragma unroll
            for (int j = 0; j < 6; ++j) {
                float w = (m == 0) ? wv[j].x : (m == 1) ? wv[j].y : (m == 2) ? wv[j].z : wv[j].w;
                acc[j][0] += w * bv[m].x;
                acc[j][1] += w * bv[m].y;
            }
        }
    }
    int k = k0 + ktl * 2;
#pragma unroll
    for (int j = 0; j < 6; ++j) {
        int q = pt + 16 * j;
        if (k + 1 < L_) {
            *(float2*)&W[(size_t)q * L_ + k] = make_float2(acc[j][0] * 0.125f, acc[j][1] * 0.125f);
        } else if (k < L_) {
            W[(size_t)q * L_ + k] = acc[j][0] * 0.125f;
        }
    }
}

// ------- Kernel 6: one-wave-per-row softmax over L_ ----
__global__ __launch_bounds__(64) void k_softmax_rows(float* __restrict__ base_g) {
    float* base = base_g + (size_t)blockIdx.x * L_;
    int lane = threadIdx.x;
    float v[8];
    float m = -FLT_MAX;
#pragma unroll
    for (int i = 0; i < 8; ++i) {
        int idx = i * 64 + lane;
        v[i] = (idx < L_) ? base[idx] : -FLT_MAX;
        m = fmaxf(m, v[i]);
    }
    for (int off = 32; off; off >>= 1) m = fmaxf(m, __shfl_xor(m, off));
    float s = 0.f;
#pragma unroll
    for (int i = 0; i < 8; ++i) {
        float e = expf(v[i] - m);
        v[i] = e; s += e;
    }
    for (int off = 32; off; off >>= 1) s += __shfl_xor(s, off);
    float inv = 1.f / s;
#pragma unroll
    for (int i = 0; i < 8; ++i) {
        int idx = i * 64 + lane;
        if (idx < L_) base[idx] = v[i] * inv;
    }
}

// ------- Kernel 7: mid masked raw scores, grid (B, 8 k-tiles) ----------
__global__ __launch_bounds__(256) void k_mid_scores(float* ws) {
    int b = blockIdx.x, kt = blockIdx.y, tid = threadIdx.x;
    const float* ET = ws + OFF_ET + (size_t)b * L_ * D_;
    float* WM = ws + OFF_WM + (size_t)b * MID_ * L_;
    __shared__ float qv[7][68];
    __shared__ float Bl[64 * 65];
    for (int idx = tid; idx < 7 * 16; idx += 256) {
        int q = idx >> 4, d4 = (idx & 15) * 4;
        *(float4*)&qv[q][d4] = *(const float4*)&ET[(size_t)(L_ - MID_ + q) * D_ + d4];
    }
    int k0 = kt * 64;
    for (int idx = tid; idx < 64 * 16; idx += 256) {
        int kk = idx >> 4, d4 = (idx & 15) * 4;
        float4 v = (k0 + kk < L_) ? *(const float4*)&ET[(size_t)(k0 + kk) * D_ + d4]
                                  : make_float4(0.f, 0.f, 0.f, 0.f);
        Bl[kk * 65 + d4 + 0] = v.x;
        Bl[kk * 65 + d4 + 1] = v.y;
        Bl[kk * 65 + d4 + 2] = v.z;
        Bl[kk * 65 + d4 + 3] = v.w;
    }
    __syncthreads();
    int klane = tid & 63, qs = tid >> 6;
    int q0 = qs, q1 = qs + 4;
    float a0 = 0.f, a1 = 0.f;
    for (int d = 0; d < 64; ++d) {
        float e = Bl[klane * 65 + d];
        a0 += e * qv[q0][d];
        if (q1 < 7) a1 += e * qv[q1][d];
    }
    int k = k0 + klane;
    if (k < L_) {
        WM[(size_t)q0 * L_ + k] = (k < L_ - MID_ + q0) ? a0 * 0.125f : -FLT_MAX;
        if (q1 < 7)
            WM[(size_t)q1 * L_ + k] = (k < L_ - MID_ + q1) ? a1 * 0.125f : -FLT_MAX;
    }
}

// ------- Kernel 8: season PV — attn weights streamed per-thread from ------
// global, Xs chunk in LDS. grid (B, 8 n-tiles of 32), block 256. No atomics.
__global__ __launch_bounds__(256, 2) void k_season_pv(const float* __restrict__ ws_c,
                                                      float* __restrict__ out0) {
    int b = blockIdx.x, nt = blockIdx.y, tid = threadIdx.x;
    __shared__ float Xl[32 * 36];         // [k-local][n-local 32], pad 36
    const float* Wse = ws_c + OFF_WSE + (size_t)b * P_ * L_;
    const float* Xsb = ws_c + OFF_XS + (size_t)b * L_ * N_ + nt * 32;
    int pt = tid >> 4, ntl = tid & 15;
    const float* wrow[6];
#pragma unroll
    for (int j = 0; j < 6; ++j) wrow[j] = Wse + (size_t)(pt + 16 * j) * L_;
    float acc[6][2] = {};
    float4 xr;
    int frow = tid >> 3, fn4 = (tid & 7) * 4;

    auto fetchX = [&](int k0) {
        xr = (k0 + frow < L_) ? *(const float4*)&Xsb[(size_t)(k0 + frow) * N_ + fn4]
                              : make_float4(0.f, 0.f, 0.f, 0.f);
    };
    auto stageX = [&]() {
        *(float4*)&Xl[frow * 36 + fn4] = xr;
    };
    auto computeC = [&](int k0, int nk) {
#pragma unroll
        for (int lc = 0; lc < nk; lc += 4) {
            float4 wv[6];
#pragma unroll
            for (int j = 0; j < 6; ++j) wv[j] = *(const float4*)&wrow[j][k0 + lc];
            float2 bv[4];
#pragma unroll
            for (int t = 0; t < 4; ++t) bv[t] = *(const float2*)&Xl[(lc + t) * 36 + ntl * 2];
#pragma unroll
            for (int t = 0; t < 4; ++t) {
#pragma unroll
                for (int j = 0; j < 6; ++j) {
                    float w = (t == 0) ? wv[j].x : (t == 1) ? wv[j].y : (t == 2) ? wv[j].z : wv[j].w;
                    acc[j][0] += w * bv[t].x;
                    acc[j][1] += w * bv[t].y;
                }
            }
        }
    };

    fetchX(0); stageX();
    for (int c = 1; c < 16; ++c) {        // chunks: 15x32 + tail 8
        fetchX(c * 32);
        __syncthreads();
        computeC((c - 1) * 32, 32);
        __syncthreads();
        stageX();
    }
    __syncthreads();
    computeC(480, 8);

    float* o = out0 + (size_t)b * P_ * N_ + nt * 32 + ntl * 2;
#pragma unroll
    for (int j = 0; j < 6; ++j) {
        int q = pt + 16 * j;
        float2* op = (float2*)&o[(size_t)q * N_];
        float2 prev = *op;
        prev.x += acc[j][0];
        prev.y += acc[j][1];
        *op = prev;
    }
}

// ------- Kernel 9: mid PV -> out1, 8-way k-slices in one block -------------
__global__ __launch_bounds__(512) void k_mid_pv(const float* __restrict__ ws_c,
                                                float* __restrict__ out1) {
    int b = blockIdx.x, nt = blockIdx.y, tid = threadIdx.x;
    int nl = tid & 63, ks = tid >> 6;
    const float* Xs = ws_c + OFF_XS + (size_t)b * L_ * N_;
    const float* WM = ws_c + OFF_WM + (size_t)b * MID_ * L_;
    __shared__ float wl[7 * L_];
    __shared__ float part[8][7][64];
    for (int idx = tid; idx < 7 * L_; idx += 512) wl[idx] = WM[idx];
    __syncthreads();
    float acc[7] = {};
    int kbeg = ks * 61, kend = kbeg + 61;
    for (int k = kbeg; k < kend; ++k) {
        float xv = Xs[(size_t)k * N_ + nt * 64 + nl];
#pragma unroll
        for (int q = 0; q < 7; ++q) acc[q] += wl[q * L_ + k] * xv;
    }
#pragma unroll
    for (int q = 0; q < 7; ++q) part[ks][q][nl] = acc[q];
    __syncthreads();
    if (ks == 0) {
#pragma unroll
        for (int q = 0; q < 7; ++q) {
            float v = 0.f;
#pragma unroll
            for (int s = 0; s < 8; ++s) v += part[s][q][nl];
            out1[((size_t)b * MID_ + q) * N_ + nt * 64 + nl] = v;
        }
    }
}

extern "C" void kernel_launch(void* const* d_in, const int* in_sizes, int n_in,
                              void* d_out, int out_size, void* d_ws, size_t ws_size,
                              hipStream_t stream) {
    (void)in_sizes; (void)n_in; (void)out_size; (void)ws_size;
    const float* X  = (const float*)d_in[0];
    const float* T  = (const float*)d_in[1];
    const float* Wt = (const float*)d_in[2];
    const float* bt = (const float*)d_in[3];
    const float* w0 = (const float*)d_in[4];
    const float* b0 = (const float*)d_in[5];
    const float* Wp = (const float*)d_in[6];
    const float* Bp = (const float*)d_in[7];
    float* out = (float*)d_out;
    float* ws  = (float*)d_ws;
    float* out1 = out + (size_t)B_ * P_ * N_;

    hipLaunchKernelGGL(k_trend, dim3(B_, 8), dim3(256), 0, stream, X, ws);
    hipLaunchKernelGGL(k_embed, dim3((B_ * (L_ + P_) * D_) / 256), dim3(256), 0, stream,
                       T, w0, b0, Wp, Bp, ws);
    hipLaunchKernelGGL(k_trend_gemm, dim3(N_, 2), dim3(256), 0, stream, Wt, ws, ws + OFF_PART);
    hipLaunchKernelGGL(k_reduce_trend, dim3(8, 96), dim3(256), 0, stream, ws + OFF_PART, bt, out);
    hipLaunchKernelGGL(k_season_scores, dim3(B_, 16), dim3(256), 0, stream, ws);
    hipLaunchKernelGGL(k_softmax_rows, dim3(B_ * P_), dim3(64), 0, stream, ws + OFF_WSE);
    hipLaunchKernelGGL(k_mid_scores, dim3(B_, 8), dim3(256), 0, stream, ws);
    hipLaunchKernelGGL(k_softmax_rows, dim3(B_ * MID_), dim3(64), 0, stream, ws + OFF_WM);
    hipLaunchKernelGGL(k_season_pv, dim3(B_, 8), dim3(256), 0, stream, ws, out);
    hipLaunchKernelGGL(k_mid_pv, dim3(B_, 4), dim3(512), 0, stream, ws, out1);
}

// Round 7
// 237.571 us; speedup vs baseline: 1.4554x; 1.4554x over previous
//
#include <hip/hip_runtime.h>
#include <math.h>
#include <float.h>

#define B_ 64
#define S_ 512
#define N_ 256
#define P_ 96
#define D_ 64
#define WIN_ 24
#define L_ 488   // S_ - WIN_
#define MID_ 7
#define PB_ (P_*B_)   // 6144

typedef unsigned short u16;
typedef __attribute__((ext_vector_type(4))) float floatx4;
typedef __attribute__((ext_vector_type(8))) short bf16x8;
#define MFMA16(a,b,c) __builtin_amdgcn_mfma_f32_16x16x32_bf16(a,b,c,0,0,0)

// workspace layout (BYTE offsets)
#define OFF_XSB  ((size_t)0)                 // Xs  bf16 [B][L][N]
#define OFF_XST  ((size_t)15990784)          // XsT bf16 [B][N][L]
#define OFF_TRT  ((size_t)31981568)          // trT bf16 [N][B][L]
#define OFF_ET   ((size_t)47972352)          // embed_t fp32 [B][L][D]
#define OFF_EN   ((size_t)55967744)          // embed_next fp32 [B][P][D]
#define OFF_WSE  ((size_t)57540608)          // season scores fp32 [B][P][L]
#define OFF_WSEB ((size_t)69533696)          // season weights bf16 [B][P][L]
#define OFF_WM   ((size_t)75530240)          // mid weights fp32 [B][MID][L]
// total 76,404,736 B. trend partials fp32 [N][P][B] (6.3 MB) alias WSE;
// consumed by k_reduce_trend BEFORE k_season_scores writes WSE.
#define OFF_PART OFF_WSE

__device__ inline u16 f2bf(float f) {
    union { float f; unsigned u; } v; v.f = f;
    unsigned r = v.u + 0x7FFFu + ((v.u >> 16) & 1u);
    return (u16)(r >> 16);
}
__device__ inline float bf2f(u16 u) {
    union { unsigned u; float f; } v; v.u = ((unsigned)u) << 16;
    return v.f;
}

// ---------------- Kernel 1: rolling-mean trend + season ----------------
// grid (B, 8), block 256 (thread = n). Emits Xs bf16 [B][L][N] (coalesced),
// XsT bf16 [B][N][L] and trT bf16 [N][B][L] via LDS transpose.
__global__ __launch_bounds__(256) void k_trend(const float* __restrict__ X,
                                               u16* __restrict__ XSB,
                                               u16* __restrict__ XST,
                                               u16* __restrict__ TRT) {
    int b = blockIdx.x, tile = blockIdx.y, n = threadIdx.x;
    __shared__ u16 tr_tile[256][62];
    __shared__ u16 xs_tile[256][62];
    const float* Xb = X + (size_t)b * S_ * N_ + n;
    int s1 = WIN_ + tile * 61;
    float wsum = 0.f;
    for (int s = s1 - WIN_; s < s1; ++s) wsum += Xb[(size_t)s * N_];
    for (int i = 0; i < 61; ++i) {
        int s = s1 + i, l = s - WIN_;
        float xv = Xb[(size_t)s * N_];
        wsum += xv - Xb[(size_t)(s - WIN_) * N_];
        float tr = wsum * (1.f / WIN_);
        float xs = xv - tr;
        XSB[((size_t)b * L_ + l) * N_ + n] = f2bf(xs);   // coalesced 2B
        tr_tile[n][i] = f2bf(tr);
        xs_tile[n][i] = f2bf(xs);
    }
    __syncthreads();
    int lane = threadIdx.x & 63, w = threadIdx.x >> 6;
    int l0 = tile * 61;
    for (int r = w; r < 256; r += 4) {
        if (lane < 61) {
            TRT[(size_t)r * (B_ * L_) + (size_t)b * L_ + l0 + lane] = tr_tile[r][lane];
            XST[((size_t)b * N_ + r) * L_ + l0 + lane] = xs_tile[r][lane];
        }
    }
}

// ---------------- Kernel 2: time2vec embeds (fp32 out — scores need it) ----
__global__ __launch_bounds__(256) void k_embed(const float* __restrict__ T,
                                               const float* __restrict__ w0,
                                               const float* __restrict__ b0,
                                               const float* __restrict__ Wp,
                                               const float* __restrict__ Bp,
                                               float* __restrict__ ET,
                                               float* __restrict__ EN) {
    int idx = blockIdx.x * 256 + threadIdx.x;
    int d = idx & 63;
    int rest = idx >> 6;
    int pos = rest % (L_ + P_);
    int b = rest / (L_ + P_);
    float t;
    float* dst;
    if (pos < L_) {
        t = T[(size_t)b * S_ + WIN_ + pos];
        dst = ET + ((size_t)b * L_ + pos) * D_ + d;
    } else {
        int p = pos - L_;
        t = T[(size_t)b * S_ + (S_ - 1)] + (float)(p + 1);
        dst = EN + ((size_t)b * P_ + p) * D_ + d;
    }
    float v = (d == 0) ? (t * w0[0] + b0[0]) : sinf(t * Wp[d - 1] + Bp[d - 1]);
    *dst = v;
}

// ------- Kernel 3: trend GEMM via MFMA bf16. grid (N_), block 256. --------
// C[96 p][64 b] = Wn[96][488] . trTn[64][488]^T, K-chunks of 32, prefetched.
// bf16-safe: operands O(1/488) x O(0.3), fp32 accumulate, no exp downstream.
__global__ __launch_bounds__(256) void k_trend_gemm(const float* __restrict__ Wt_g,
                                                    const u16* __restrict__ TRT,
                                                    float* __restrict__ part) {
    int n = blockIdx.x, tid = threadIdx.x;
    int lane = tid & 63, wv = tid >> 6;
    int fr = lane & 15, quad = lane >> 4;
    __shared__ __align__(16) char smem_raw[24576];
    u16* Al = (u16*)smem_raw;            // [96][40] bf16
    u16* Bl = Al + 96 * 40;              // [64][40] bf16
    float* Cst = (float*)smem_raw;       // epilogue [96][64]
    const float* Wn = Wt_g + (size_t)n * P_ * L_;
    const u16* Tn = TRT + (size_t)n * (B_ * L_);
    floatx4 acc[6];
#pragma unroll
    for (int j = 0; j < 6; ++j) acc[j] = (floatx4){0.f, 0.f, 0.f, 0.f};
    float4 wr[3];
    uint4 br;

    auto fetch = [&](int c) {
        int k0 = c * 32, cur = L_ - k0;
#pragma unroll
        for (int t = 0; t < 3; ++t) {
            int u = tid + t * 256, row = u >> 3, c4 = (u & 7) * 4;
            wr[t] = (c4 < cur) ? *(const float4*)&Wn[(size_t)row * L_ + k0 + c4]
                               : make_float4(0.f, 0.f, 0.f, 0.f);
        }
        int brow = tid >> 2, c8 = (tid & 3) * 8;
        br = (c8 < cur) ? *(const uint4*)&Tn[(size_t)brow * L_ + k0 + c8]
                        : make_uint4(0u, 0u, 0u, 0u);
    };
    auto stage = [&]() {
#pragma unroll
        for (int t = 0; t < 3; ++t) {
            int u = tid + t * 256, row = u >> 3, c4 = (u & 7) * 4;
            ushort4 pk;
            pk.x = f2bf(wr[t].x); pk.y = f2bf(wr[t].y);
            pk.z = f2bf(wr[t].z); pk.w = f2bf(wr[t].w);
            *(ushort4*)&Al[row * 40 + c4] = pk;
        }
        int brow = tid >> 2, c8 = (tid & 3) * 8;
        *(uint4*)&Bl[brow * 40 + c8] = br;
    };
    auto compute = [&]() {
        bf16x8 bfr = *(const bf16x8*)&Bl[(wv * 16 + fr) * 40 + quad * 8];
#pragma unroll
        for (int j = 0; j < 6; ++j) {
            bf16x8 afr = *(const bf16x8*)&Al[(j * 16 + fr) * 40 + quad * 8];
            acc[j] = MFMA16(afr, bfr, acc[j]);
        }
    };

    fetch(0); stage();
    for (int c = 1; c < 16; ++c) {
        fetch(c);
        __syncthreads();
        compute();
        __syncthreads();
        stage();
    }
    __syncthreads();
    compute();

    __syncthreads();
#pragma unroll
    for (int j = 0; j < 6; ++j)
#pragma unroll
        for (int r = 0; r < 4; ++r)
            Cst[(j * 16 + quad * 4 + r) * 64 + wv * 16 + fr] = acc[j][r];
    __syncthreads();
    float* dstp = part + (size_t)n * PB_;
    for (int u = tid; u < 1536; u += 256)
        *(float4*)&dstp[u * 4] = *(const float4*)&Cst[u * 4];
}

// ------- Kernel 4: transpose partial[n][p][b] + bias -> out0 [b][p][n] -----
__global__ __launch_bounds__(256) void k_reduce_trend(const float* __restrict__ part,
                                                      const float* __restrict__ bt,
                                                      float* __restrict__ out0) {
    int nt = blockIdx.x, p = blockIdx.y, tid = threadIdx.x;
    __shared__ float t[32][65];
    int n0 = nt * 32;
    for (int idx = tid; idx < 2048; idx += 256) {
        int i = idx >> 6, j = idx & 63;
        t[i][j] = part[(size_t)(n0 + i) * PB_ + p * 64 + j];
    }
    __syncthreads();
    for (int idx = tid; idx < 2048; idx += 256) {
        int bb = idx >> 5, nl = idx & 31;
        out0[((size_t)bb * P_ + p) * N_ + n0 + nl] = t[nl][bb] + bt[(size_t)p * N_ + n0 + nl];
    }
}

// ------- Kernel 5: season scores, FP32 VALU (scores are O(2500): ---------
// softmax is exp-sensitive, bf16 operands forbidden here). grid (B, 8).
__global__ __launch_bounds__(256) void k_season_scores(const float* __restrict__ EN_g,
                                                       const float* __restrict__ ET_g,
                                                       float* __restrict__ WSE) {
    int b = blockIdx.x, kt = blockIdx.y, tid = threadIdx.x;
    const float* EN = EN_g + (size_t)b * P_ * D_;
    const float* ET = ET_g + (size_t)b * L_ * D_;
    float* W = WSE + (size_t)b * P_ * L_;
    __shared__ float Al[96][68];
    __shared__ float Bl[64][68];
    for (int idx = tid; idx < 96 * 16; idx += 256) {
        int q = idx >> 4, d4 = (idx & 15) * 4;
        *(float4*)&Al[q][d4] = *(const float4*)&EN[q * 64 + d4];
    }
    int k0 = kt * 64;
    for (int idx = tid; idx < 64 * 16; idx += 256) {
        int kk = idx >> 4, d4 = (idx & 15) * 4;
        float4 v = (k0 + kk < L_) ? *(const float4*)&ET[(size_t)(k0 + kk) * D_ + d4]
                                  : make_float4(0.f, 0.f, 0.f, 0.f);
        *(float4*)&Bl[kk][d4] = v;
    }
    __syncthreads();
    int qt = tid >> 4, ktl = tid & 15;
    float acc[6][4] = {};
    for (int d = 0; d < 64; d += 4) {
        float4 av[6], bv[4];
#pragma unroll
        for (int j = 0; j < 6; ++j) av[j] = *(const float4*)&Al[qt + 16 * j][d];
#pragma unroll
        for (int i = 0; i < 4; ++i) bv[i] = *(const float4*)&Bl[ktl + 16 * i][d];
#pragma unroll
        for (int j = 0; j < 6; ++j)
#pragma unroll
            for (int i = 0; i < 4; ++i)
                acc[j][i] += av[j].x * bv[i].x + av[j].y * bv[i].y +
                             av[j].z * bv[i].z + av[j].w * bv[i].w;
    }
#pragma unroll
    for (int j = 0; j < 6; ++j) {
        int q = qt + 16 * j;
#pragma unroll
        for (int i = 0; i < 4; ++i) {
            int k = k0 + ktl + 16 * i;
            if (k < L_) W[(size_t)q * L_ + k] = acc[j][i] * 0.125f;
        }
    }
}

// ------- Kernel 6a: softmax rows fp32 -> bf16 weights (season) ------------
// Weights are O(<=1) and feed a linear PV: bf16-safe.
__global__ __launch_bounds__(64) void k_softmax_se(const float* __restrict__ WSE,
                                                   u16* __restrict__ WSEB) {
    size_t row = blockIdx.x;
    const float* base = WSE + row * L_;
    u16* out = WSEB + row * L_;
    int lane = threadIdx.x;
    float v[8];
    float m = -FLT_MAX;
#pragma unroll
    for (int i = 0; i < 8; ++i) {
        int idx = i * 64 + lane;
        v[i] = (idx < L_) ? base[idx] : -FLT_MAX;
        m = fmaxf(m, v[i]);
    }
    for (int off = 32; off; off >>= 1) m = fmaxf(m, __shfl_xor(m, off));
    float s = 0.f;
#pragma unroll
    for (int i = 0; i < 8; ++i) {
        float e = expf(v[i] - m);
        v[i] = e; s += e;
    }
    for (int off = 32; off; off >>= 1) s += __shfl_xor(s, off);
    float inv = 1.f / s;
#pragma unroll
    for (int i = 0; i < 8; ++i) {
        int idx = i * 64 + lane;
        if (idx < L_) out[idx] = f2bf(v[i] * inv);
    }
}

// ------- Kernel 6b: softmax rows fp32 in place (mid) ----------------------
__global__ __launch_bounds__(64) void k_softmax_mid(float* __restrict__ base_g) {
    float* base = base_g + (size_t)blockIdx.x * L_;
    int lane = threadIdx.x;
    float v[8];
    float m = -FLT_MAX;
#pragma unroll
    for (int i = 0; i < 8; ++i) {
        int idx = i * 64 + lane;
        v[i] = (idx < L_) ? base[idx] : -FLT_MAX;
        m = fmaxf(m, v[i]);
    }
    for (int off = 32; off; off >>= 1) m = fmaxf(m, __shfl_xor(m, off));
    float s = 0.f;
#pragma unroll
    for (int i = 0; i < 8; ++i) {
        float e = expf(v[i] - m);
        v[i] = e; s += e;
    }
    for (int off = 32; off; off >>= 1) s += __shfl_xor(s, off);
    float inv = 1.f / s;
#pragma unroll
    for (int i = 0; i < 8; ++i) {
        int idx = i * 64 + lane;
        if (idx < L_) base[idx] = v[i] * inv;
    }
}

// ------- Kernel 7: mid masked raw scores, FP32 (same exp-sensitivity) -----
__global__ __launch_bounds__(256) void k_mid_scores(const float* __restrict__ ET_g,
                                                    float* __restrict__ WM_g) {
    int b = blockIdx.x, kt = blockIdx.y, tid = threadIdx.x;
    const float* ET = ET_g + (size_t)b * L_ * D_;
    float* WM = WM_g + (size_t)b * MID_ * L_;
    __shared__ float qv[7][68];
    __shared__ float Bl[64 * 65];
    for (int idx = tid; idx < 7 * 16; idx += 256) {
        int q = idx >> 4, d4 = (idx & 15) * 4;
        *(float4*)&qv[q][d4] = *(const float4*)&ET[(size_t)(L_ - MID_ + q) * D_ + d4];
    }
    int k0 = kt * 64;
    for (int idx = tid; idx < 64 * 16; idx += 256) {
        int kk = idx >> 4, d4 = (idx & 15) * 4;
        float4 v = (k0 + kk < L_) ? *(const float4*)&ET[(size_t)(k0 + kk) * D_ + d4]
                                  : make_float4(0.f, 0.f, 0.f, 0.f);
        Bl[kk * 65 + d4 + 0] = v.x;
        Bl[kk * 65 + d4 + 1] = v.y;
        Bl[kk * 65 + d4 + 2] = v.z;
        Bl[kk * 65 + d4 + 3] = v.w;
    }
    __syncthreads();
    int klane = tid & 63, qs = tid >> 6;
    int q0 = qs, q1 = qs + 4;
    float a0 = 0.f, a1 = 0.f;
    for (int d = 0; d < 64; ++d) {
        float e = Bl[klane * 65 + d];
        a0 += e * qv[q0][d];
        if (q1 < 7) a1 += e * qv[q1][d];
    }
    int k = k0 + klane;
    if (k < L_) {
        WM[(size_t)q0 * L_ + k] = (k < L_ - MID_ + q0) ? a0 * 0.125f : -FLT_MAX;
        if (q1 < 7)
            WM[(size_t)q1 * L_ + k] = (k < L_ - MID_ + q1) ? a1 * 0.125f : -FLT_MAX;
    }
}

// ------- Kernel 8: season PV via MFMA. grid (B, 4 n-tiles), block 256. ----
// C[96 q][64 n] = Wse[96][488] . XsT_tile[64][488]^T, RMW into out0.
__global__ __launch_bounds__(256) void k_season_pv(const u16* __restrict__ WSEB,
                                                   const u16* __restrict__ XST,
                                                   float* __restrict__ out0) {
    int b = blockIdx.x, nt = blockIdx.y, tid = threadIdx.x;
    int lane = tid & 63, wv = tid >> 6;
    int fr = lane & 15, quad = lane >> 4;
    __shared__ __align__(16) char smem_raw[24576];
    u16* Al = (u16*)smem_raw;            // Wse [96][40]
    u16* Bl = Al + 96 * 40;              // XsT [64][40]
    float* Cst = (float*)smem_raw;
    const u16* Wa = WSEB + (size_t)b * P_ * L_;
    const u16* Xb = XST + ((size_t)b * N_ + nt * 64) * L_;
    floatx4 acc[6];
#pragma unroll
    for (int j = 0; j < 6; ++j) acc[j] = (floatx4){0.f, 0.f, 0.f, 0.f};
    uint4 ar[2], br;

    auto fetch = [&](int c) {
        int k0 = c * 32, cur = L_ - k0;
#pragma unroll
        for (int t = 0; t < 2; ++t) {
            int u = tid + t * 256;
            ar[t] = make_uint4(0u, 0u, 0u, 0u);
            if (u < 384) {
                int row = u >> 2, c8 = (u & 3) * 8;
                if (c8 < cur) ar[t] = *(const uint4*)&Wa[(size_t)row * L_ + k0 + c8];
            }
        }
        int brow = tid >> 2, c8 = (tid & 3) * 8;
        br = (c8 < cur) ? *(const uint4*)&Xb[(size_t)brow * L_ + k0 + c8]
                        : make_uint4(0u, 0u, 0u, 0u);
    };
    auto stage = [&]() {
#pragma unroll
        for (int t = 0; t < 2; ++t) {
            int u = tid + t * 256;
            if (u < 384) {
                int row = u >> 2, c8 = (u & 3) * 8;
                *(uint4*)&Al[row * 40 + c8] = ar[t];
            }
        }
        int brow = tid >> 2, c8 = (tid & 3) * 8;
        *(uint4*)&Bl[brow * 40 + c8] = br;
    };
    auto compute = [&]() {
        bf16x8 bfr = *(const bf16x8*)&Bl[(wv * 16 + fr) * 40 + quad * 8];
#pragma unroll
        for (int j = 0; j < 6; ++j) {
            bf16x8 afr = *(const bf16x8*)&Al[(j * 16 + fr) * 40 + quad * 8];
            acc[j] = MFMA16(afr, bfr, acc[j]);
        }
    };

    fetch(0); stage();
    for (int c = 1; c < 16; ++c) {
        fetch(c);
        __syncthreads();
        compute();
        __syncthreads();
        stage();
    }
    __syncthreads();
    compute();

    __syncthreads();
#pragma unroll
    for (int j = 0; j < 6; ++j)
#pragma unroll
        for (int r = 0; r < 4; ++r)
            Cst[(j * 16 + quad * 4 + r) * 64 + wv * 16 + fr] = acc[j][r];
    __syncthreads();
    float* o = out0 + (size_t)b * P_ * N_ + nt * 64;
    for (int u = tid; u < 1536; u += 256) {
        int p = u >> 4, c4 = (u & 15) * 4;
        float4* op = (float4*)&o[(size_t)p * N_ + c4];
        float4 pv = *op;
        const float* cs = &Cst[p * 64 + c4];
        pv.x += cs[0]; pv.y += cs[1]; pv.z += cs[2]; pv.w += cs[3];
        *op = pv;
    }
}

// ------- Kernel 9: mid PV -> out1 (bf16 Xs, fp32 weights) -----------------
__global__ __launch_bounds__(512) void k_mid_pv(const u16* __restrict__ XSB,
                                                const float* __restrict__ WM_g,
                                                float* __restrict__ out1) {
    int b = blockIdx.x, nt = blockIdx.y, tid = threadIdx.x;
    int nl = tid & 63, ks = tid >> 6;
    const u16* Xs = XSB + (size_t)b * L_ * N_;
    const float* WM = WM_g + (size_t)b * MID_ * L_;
    __shared__ float wl[7 * L_];
    __shared__ float part[8][7][64];
    for (int idx = tid; idx < 7 * L_; idx += 512) wl[idx] = WM[idx];
    __syncthreads();
    float acc[7] = {};
    int kbeg = ks * 61, kend = kbeg + 61;
    for (int k = kbeg; k < kend; ++k) {
        float xv = bf2f(Xs[(size_t)k * N_ + nt * 64 + nl]);
#pragma unroll
        for (int q = 0; q < 7; ++q) acc[q] += wl[q * L_ + k] * xv;
    }
#pragma unroll
    for (int q = 0; q < 7; ++q) part[ks][q][nl] = acc[q];
    __syncthreads();
    if (ks == 0) {
#pragma unroll
        for (int q = 0; q < 7; ++q) {
            float v = 0.f;
#pragma unroll
            for (int s = 0; s < 8; ++s) v += part[s][q][nl];
            out1[((size_t)b * MID_ + q) * N_ + nt * 64 + nl] = v;
        }
    }
}

extern "C" void kernel_launch(void* const* d_in, const int* in_sizes, int n_in,
                              void* d_out, int out_size, void* d_ws, size_t ws_size,
                              hipStream_t stream) {
    (void)in_sizes; (void)n_in; (void)out_size; (void)ws_size;
    const float* X  = (const float*)d_in[0];
    const float* T  = (const float*)d_in[1];
    const float* Wt = (const float*)d_in[2];
    const float* bt = (const float*)d_in[3];
    const float* w0 = (const float*)d_in[4];
    const float* b0 = (const float*)d_in[5];
    const float* Wp = (const float*)d_in[6];
    const float* Bp = (const float*)d_in[7];
    float* out = (float*)d_out;
    char* w8 = (char*)d_ws;
    float* out1 = out + (size_t)B_ * P_ * N_;

    u16*   XSB  = (u16*)(w8 + OFF_XSB);
    u16*   XST  = (u16*)(w8 + OFF_XST);
    u16*   TRT  = (u16*)(w8 + OFF_TRT);
    float* ET   = (float*)(w8 + OFF_ET);
    float* EN   = (float*)(w8 + OFF_EN);
    float* WSE  = (float*)(w8 + OFF_WSE);
    u16*   WSEB = (u16*)(w8 + OFF_WSEB);
    float* WM   = (float*)(w8 + OFF_WM);
    float* PART = (float*)(w8 + OFF_PART);

    hipLaunchKernelGGL(k_trend, dim3(B_, 8), dim3(256), 0, stream, X, XSB, XST, TRT);
    hipLaunchKernelGGL(k_embed, dim3((B_ * (L_ + P_) * D_) / 256), dim3(256), 0, stream,
                       T, w0, b0, Wp, Bp, ET, EN);
    hipLaunchKernelGGL(k_trend_gemm, dim3(N_), dim3(256), 0, stream, Wt, TRT, PART);
    hipLaunchKernelGGL(k_reduce_trend, dim3(8, 96), dim3(256), 0, stream, PART, bt, out);
    hipLaunchKernelGGL(k_season_scores, dim3(B_, 8), dim3(256), 0, stream, EN, ET, WSE);
    hipLaunchKernelGGL(k_softmax_se, dim3(B_ * P_), dim3(64), 0, stream, WSE, WSEB);
    hipLaunchKernelGGL(k_mid_scores, dim3(B_, 8), dim3(256), 0, stream, ET, WM);
    hipLaunchKernelGGL(k_softmax_mid, dim3(B_ * MID_), dim3(64), 0, stream, WM);
    hipLaunchKernelGGL(k_season_pv, dim3(B_, 4), dim3(256), 0, stream, WSEB, XST, out);
    hipLaunchKernelGGL(k_mid_pv, dim3(B_, 4), dim3(512), 0, stream, XSB, WM, out1);
}

// Round 8
// 212.761 us; speedup vs baseline: 1.6251x; 1.1166x over previous
//
#include <hip/hip_runtime.h>
#include <math.h>
#include <float.h>

#define B_ 64
#define S_ 512
#define N_ 256
#define P_ 96
#define D_ 64
#define WIN_ 24
#define L_ 488   // S_ - WIN_
#define MID_ 7
#define PB_ (P_*B_)   // 6144

typedef unsigned short u16;
typedef __attribute__((ext_vector_type(4))) float floatx4;
typedef __attribute__((ext_vector_type(8))) short bf16x8;
#define MFMA16(a,b,c) __builtin_amdgcn_mfma_f32_16x16x32_bf16(a,b,c,0,0,0)

// workspace layout (BYTE offsets)
#define OFF_XSB  ((size_t)0)                 // Xs  bf16 [B][L][N]
#define OFF_XST  ((size_t)15990784)          // XsT bf16 [B][N][L]
#define OFF_TRT  ((size_t)31981568)          // trT bf16 [N][B][L]
#define OFF_ET   ((size_t)47972352)          // embed_t fp32 [B][L][D]
#define OFF_EN   ((size_t)55967744)          // embed_next fp32 [B][P][D]
#define OFF_WSE  ((size_t)57540608)          // season scores fp32 [B][P][L]
#define OFF_WSEB ((size_t)69533696)          // season weights bf16 [B][P][L]
#define OFF_WM   ((size_t)75530240)          // mid weights fp32 [B][MID][L]
// trend partials fp32 [N][P][B] (6.3 MB) alias WSE; consumed by
// k_reduce_trend BEFORE k_season_scores writes WSE.
#define OFF_PART OFF_WSE

__device__ inline u16 f2bf(float f) {
    union { float f; unsigned u; } v; v.f = f;
    unsigned r = v.u + 0x7FFFu + ((v.u >> 16) & 1u);
    return (u16)(r >> 16);
}
__device__ inline float bf2f(u16 u) {
    union { unsigned u; float f; } v; v.u = ((unsigned)u) << 16;
    return v.f;
}

// ---------------- Kernel 1: rolling-mean trend + season ----------------
// grid (B, 16 l-tiles of 32), block 256 (thread = n). LDS 34 KB -> 4 blk/CU.
// Row stride 34 u16 = 17 dwords (gcd(17,32)=1): conflict-free tile writes.
__global__ __launch_bounds__(256) void k_trend(const float* __restrict__ X,
                                               u16* __restrict__ XSB,
                                               u16* __restrict__ XST,
                                               u16* __restrict__ TRT) {
    int b = blockIdx.x, tile = blockIdx.y, n = threadIdx.x;
    __shared__ u16 tr_tile[256][34];
    __shared__ u16 xs_tile[256][34];
    const float* Xb = X + (size_t)b * S_ * N_ + n;
    int l0 = tile * 32;
    int cur = L_ - l0; if (cur > 32) cur = 32;    // 32 or 8 (tail)
    int s1 = WIN_ + l0;
    float wsum = 0.f;
    for (int s = s1 - WIN_; s < s1; ++s) wsum += Xb[(size_t)s * N_];
    for (int i = 0; i < cur; ++i) {
        int s = s1 + i, l = l0 + i;
        float xv = Xb[(size_t)s * N_];
        wsum += xv - Xb[(size_t)(s - WIN_) * N_];
        float tr = wsum * (1.f / WIN_);
        float xs = xv - tr;
        XSB[((size_t)b * L_ + l) * N_ + n] = f2bf(xs);   // coalesced 2B
        tr_tile[n][i] = f2bf(tr);
        xs_tile[n][i] = f2bf(xs);
    }
    __syncthreads();
    int wv = threadIdx.x >> 6, lane = threadIdx.x & 63;
    int half = lane >> 5, c = lane & 31;          // 2 rows per instruction
    if (c < cur) {
        for (int it = 0; it < 32; ++it) {
            int r = it * 8 + wv * 2 + half;
            TRT[(size_t)r * (B_ * L_) + (size_t)b * L_ + l0 + c] = tr_tile[r][c];
            XST[((size_t)b * N_ + r) * L_ + l0 + c] = xs_tile[r][c];
        }
    }
}

// ---------------- Kernel 2: time2vec embeds (fp32 out — scores need it) ----
__global__ __launch_bounds__(256) void k_embed(const float* __restrict__ T,
                                               const float* __restrict__ w0,
                                               const float* __restrict__ b0,
                                               const float* __restrict__ Wp,
                                               const float* __restrict__ Bp,
                                               float* __restrict__ ET,
                                               float* __restrict__ EN) {
    int idx = blockIdx.x * 256 + threadIdx.x;
    int d = idx & 63;
    int rest = idx >> 6;
    int pos = rest % (L_ + P_);
    int b = rest / (L_ + P_);
    float t;
    float* dst;
    if (pos < L_) {
        t = T[(size_t)b * S_ + WIN_ + pos];
        dst = ET + ((size_t)b * L_ + pos) * D_ + d;
    } else {
        int p = pos - L_;
        t = T[(size_t)b * S_ + (S_ - 1)] + (float)(p + 1);
        dst = EN + ((size_t)b * P_ + p) * D_ + d;
    }
    float v = (d == 0) ? (t * w0[0] + b0[0]) : sinf(t * Wp[d - 1] + Bp[d - 1]);
    *dst = v;
}

// ------- Kernel 3: trend GEMM via MFMA, p-split x2. grid (N_, 2). ---------
// C[48 p][64 b] = Wn[p0+48][488] . trTn[64][488]^T. 2 blocks/CU.
__global__ __launch_bounds__(256) void k_trend_gemm(const float* __restrict__ Wt_g,
                                                    const u16* __restrict__ TRT,
                                                    float* __restrict__ part) {
    int n = blockIdx.x, ph = blockIdx.y, tid = threadIdx.x;
    int lane = tid & 63, wv = tid >> 6;
    int fr = lane & 15, quad = lane >> 4;
    __shared__ __align__(16) char smem_raw[12288];
    u16* Al = (u16*)smem_raw;            // [48][40] bf16
    u16* Bl = Al + 48 * 40;              // [64][40] bf16 (ends at 8960 B)
    float* Cst = (float*)smem_raw;       // epilogue [48][64] = 12288 B
    const float* Wn = Wt_g + ((size_t)n * P_ + (size_t)ph * 48) * L_;
    const u16* Tn = TRT + (size_t)n * (B_ * L_);
    floatx4 acc[3];
#pragma unroll
    for (int j = 0; j < 3; ++j) acc[j] = (floatx4){0.f, 0.f, 0.f, 0.f};
    float4 wr[2];
    uint4 br;

    auto fetch = [&](int c) {
        int k0 = c * 32, cur = L_ - k0;
#pragma unroll
        for (int t = 0; t < 2; ++t) {
            int u = tid + t * 256;                // W: 48*8 = 384 float4
            wr[t] = make_float4(0.f, 0.f, 0.f, 0.f);
            if (u < 384) {
                int row = u >> 3, c4 = (u & 7) * 4;
                if (c4 < cur) wr[t] = *(const float4*)&Wn[(size_t)row * L_ + k0 + c4];
            }
        }
        int brow = tid >> 2, c8 = (tid & 3) * 8;  // B: 64*4 = 256 uint4
        br = (c8 < cur) ? *(const uint4*)&Tn[(size_t)brow * L_ + k0 + c8]
                        : make_uint4(0u, 0u, 0u, 0u);
    };
    auto stage = [&]() {
#pragma unroll
        for (int t = 0; t < 2; ++t) {
            int u = tid + t * 256;
            if (u < 384) {
                int row = u >> 3, c4 = (u & 7) * 4;
                ushort4 pk;
                pk.x = f2bf(wr[t].x); pk.y = f2bf(wr[t].y);
                pk.z = f2bf(wr[t].z); pk.w = f2bf(wr[t].w);
                *(ushort4*)&Al[row * 40 + c4] = pk;
            }
        }
        int brow = tid >> 2, c8 = (tid & 3) * 8;
        *(uint4*)&Bl[brow * 40 + c8] = br;
    };
    auto compute = [&]() {
        bf16x8 bfr = *(const bf16x8*)&Bl[(wv * 16 + fr) * 40 + quad * 8];
#pragma unroll
        for (int j = 0; j < 3; ++j) {
            bf16x8 afr = *(const bf16x8*)&Al[(j * 16 + fr) * 40 + quad * 8];
            acc[j] = MFMA16(afr, bfr, acc[j]);
        }
    };

    fetch(0); stage();
    for (int c = 1; c < 16; ++c) {
        fetch(c);
        __syncthreads();
        compute();
        __syncthreads();
        stage();
    }
    __syncthreads();
    compute();

    __syncthreads();
#pragma unroll
    for (int j = 0; j < 3; ++j)
#pragma unroll
        for (int r = 0; r < 4; ++r)
            Cst[(j * 16 + quad * 4 + r) * 64 + wv * 16 + fr] = acc[j][r];
    __syncthreads();
    float* dstp = part + (size_t)n * PB_ + (size_t)ph * 48 * B_;
    for (int u = tid; u < 768; u += 256)
        *(float4*)&dstp[u * 4] = *(const float4*)&Cst[u * 4];
}

// ------- Kernel 4: transpose partial[n][p][b] + bias -> out0 [b][p][n] -----
__global__ __launch_bounds__(256) void k_reduce_trend(const float* __restrict__ part,
                                                      const float* __restrict__ bt,
                                                      float* __restrict__ out0) {
    int nt = blockIdx.x, p = blockIdx.y, tid = threadIdx.x;
    __shared__ float t[32][65];
    int n0 = nt * 32;
    for (int idx = tid; idx < 2048; idx += 256) {
        int i = idx >> 6, j = idx & 63;
        t[i][j] = part[(size_t)(n0 + i) * PB_ + p * 64 + j];
    }
    __syncthreads();
    for (int idx = tid; idx < 2048; idx += 256) {
        int bb = idx >> 5, nl = idx & 31;
        out0[((size_t)bb * P_ + p) * N_ + n0 + nl] = t[nl][bb] + bt[(size_t)p * N_ + n0 + nl];
    }
}

// ------- Kernel 5: season scores, FP32 VALU (scores are O(2500): ---------
// softmax is exp-sensitive, bf16 operands forbidden here). grid (B, 8).
__global__ __launch_bounds__(256) void k_season_scores(const float* __restrict__ EN_g,
                                                       const float* __restrict__ ET_g,
                                                       float* __restrict__ WSE) {
    int b = blockIdx.x, kt = blockIdx.y, tid = threadIdx.x;
    const float* EN = EN_g + (size_t)b * P_ * D_;
    const float* ET = ET_g + (size_t)b * L_ * D_;
    float* W = WSE + (size_t)b * P_ * L_;
    __shared__ float Al[96][68];
    __shared__ float Bl[64][68];
    for (int idx = tid; idx < 96 * 16; idx += 256) {
        int q = idx >> 4, d4 = (idx & 15) * 4;
        *(float4*)&Al[q][d4] = *(const float4*)&EN[q * 64 + d4];
    }
    int k0 = kt * 64;
    for (int idx = tid; idx < 64 * 16; idx += 256) {
        int kk = idx >> 4, d4 = (idx & 15) * 4;
        float4 v = (k0 + kk < L_) ? *(const float4*)&ET[(size_t)(k0 + kk) * D_ + d4]
                                  : make_float4(0.f, 0.f, 0.f, 0.f);
        *(float4*)&Bl[kk][d4] = v;
    }
    __syncthreads();
    int qt = tid >> 4, ktl = tid & 15;
    float acc[6][4] = {};
    for (int d = 0; d < 64; d += 4) {
        float4 av[6], bv[4];
#pragma unroll
        for (int j = 0; j < 6; ++j) av[j] = *(const float4*)&Al[qt + 16 * j][d];
#pragma unroll
        for (int i = 0; i < 4; ++i) bv[i] = *(const float4*)&Bl[ktl + 16 * i][d];
#pragma unroll
        for (int j = 0; j < 6; ++j)
#pragma unroll
            for (int i = 0; i < 4; ++i)
                acc[j][i] += av[j].x * bv[i].x + av[j].y * bv[i].y +
                             av[j].z * bv[i].z + av[j].w * bv[i].w;
    }
#pragma unroll
    for (int j = 0; j < 6; ++j) {
        int q = qt + 16 * j;
#pragma unroll
        for (int i = 0; i < 4; ++i) {
            int k = k0 + ktl + 16 * i;
            if (k < L_) W[(size_t)q * L_ + k] = acc[j][i] * 0.125f;
        }
    }
}

// ------- Kernel 6a: softmax rows fp32 -> bf16 weights (season) ------------
__global__ __launch_bounds__(64) void k_softmax_se(const float* __restrict__ WSE,
                                                   u16* __restrict__ WSEB) {
    size_t row = blockIdx.x;
    const float* base = WSE + row * L_;
    u16* out = WSEB + row * L_;
    int lane = threadIdx.x;
    float v[8];
    float m = -FLT_MAX;
#pragma unroll
    for (int i = 0; i < 8; ++i) {
        int idx = i * 64 + lane;
        v[i] = (idx < L_) ? base[idx] : -FLT_MAX;
        m = fmaxf(m, v[i]);
    }
    for (int off = 32; off; off >>= 1) m = fmaxf(m, __shfl_xor(m, off));
    float s = 0.f;
#pragma unroll
    for (int i = 0; i < 8; ++i) {
        float e = expf(v[i] - m);
        v[i] = e; s += e;
    }
    for (int off = 32; off; off >>= 1) s += __shfl_xor(s, off);
    float inv = 1.f / s;
#pragma unroll
    for (int i = 0; i < 8; ++i) {
        int idx = i * 64 + lane;
        if (idx < L_) out[idx] = f2bf(v[i] * inv);
    }
}

// ------- Kernel 6b: softmax rows fp32 in place (mid) ----------------------
__global__ __launch_bounds__(64) void k_softmax_mid(float* __restrict__ base_g) {
    float* base = base_g + (size_t)blockIdx.x * L_;
    int lane = threadIdx.x;
    float v[8];
    float m = -FLT_MAX;
#pragma unroll
    for (int i = 0; i < 8; ++i) {
        int idx = i * 64 + lane;
        v[i] = (idx < L_) ? base[idx] : -FLT_MAX;
        m = fmaxf(m, v[i]);
    }
    for (int off = 32; off; off >>= 1) m = fmaxf(m, __shfl_xor(m, off));
    float s = 0.f;
#pragma unroll
    for (int i = 0; i < 8; ++i) {
        float e = expf(v[i] - m);
        v[i] = e; s += e;
    }
    for (int off = 32; off; off >>= 1) s += __shfl_xor(s, off);
    float inv = 1.f / s;
#pragma unroll
    for (int i = 0; i < 8; ++i) {
        int idx = i * 64 + lane;
        if (idx < L_) base[idx] = v[i] * inv;
    }
}

// ------- Kernel 7: mid masked raw scores, FP32, grid (B, 8) ---------------
__global__ __launch_bounds__(256) void k_mid_scores(const float* __restrict__ ET_g,
                                                    float* __restrict__ WM_g) {
    int b = blockIdx.x, kt = blockIdx.y, tid = threadIdx.x;
    const float* ET = ET_g + (size_t)b * L_ * D_;
    float* WM = WM_g + (size_t)b * MID_ * L_;
    __shared__ float qv[7][68];
    __shared__ float Bl[64 * 65];
    for (int idx = tid; idx < 7 * 16; idx += 256) {
        int q = idx >> 4, d4 = (idx & 15) * 4;
        *(float4*)&qv[q][d4] = *(const float4*)&ET[(size_t)(L_ - MID_ + q) * D_ + d4];
    }
    int k0 = kt * 64;
    for (int idx = tid; idx < 64 * 16; idx += 256) {
        int kk = idx >> 4, d4 = (idx & 15) * 4;
        float4 v = (k0 + kk < L_) ? *(const float4*)&ET[(size_t)(k0 + kk) * D_ + d4]
                                  : make_float4(0.f, 0.f, 0.f, 0.f);
        Bl[kk * 65 + d4 + 0] = v.x;
        Bl[kk * 65 + d4 + 1] = v.y;
        Bl[kk * 65 + d4 + 2] = v.z;
        Bl[kk * 65 + d4 + 3] = v.w;
    }
    __syncthreads();
    int klane = tid & 63, qs = tid >> 6;
    int q0 = qs, q1 = qs + 4;
    float a0 = 0.f, a1 = 0.f;
    for (int d = 0; d < 64; ++d) {
        float e = Bl[klane * 65 + d];
        a0 += e * qv[q0][d];
        if (q1 < 7) a1 += e * qv[q1][d];
    }
    int k = k0 + klane;
    if (k < L_) {
        WM[(size_t)q0 * L_ + k] = (k < L_ - MID_ + q0) ? a0 * 0.125f : -FLT_MAX;
        if (q1 < 7)
            WM[(size_t)q1 * L_ + k] = (k < L_ - MID_ + q1) ? a1 * 0.125f : -FLT_MAX;
    }
}

// ------- Kernel 8: season PV via MFMA, q-split x2. grid (B, 4, 2). --------
// C[48 q][64 n] = Wse[q0+48][488] . XsT_tile[64][488]^T, RMW into out0.
__global__ __launch_bounds__(256) void k_season_pv(const u16* __restrict__ WSEB,
                                                   const u16* __restrict__ XST,
                                                   float* __restrict__ out0) {
    int b = blockIdx.x, nt = blockIdx.y, qh = blockIdx.z, tid = threadIdx.x;
    int lane = tid & 63, wv = tid >> 6;
    int fr = lane & 15, quad = lane >> 4;
    __shared__ __align__(16) char smem_raw[12288];
    u16* Al = (u16*)smem_raw;            // Wse [48][40]
    u16* Bl = Al + 48 * 40;              // XsT [64][40]
    float* Cst = (float*)smem_raw;       // [48][64]
    const u16* Wa = WSEB + ((size_t)b * P_ + (size_t)qh * 48) * L_;
    const u16* Xb = XST + ((size_t)b * N_ + nt * 64) * L_;
    floatx4 acc[3];
#pragma unroll
    for (int j = 0; j < 3; ++j) acc[j] = (floatx4){0.f, 0.f, 0.f, 0.f};
    uint4 ar, br;

    auto fetch = [&](int c) {
        int k0 = c * 32, cur = L_ - k0;
        ar = make_uint4(0u, 0u, 0u, 0u);
        if (tid < 192) {                          // A: 48*4 = 192 uint4
            int row = tid >> 2, c8 = (tid & 3) * 8;
            if (c8 < cur) ar = *(const uint4*)&Wa[(size_t)row * L_ + k0 + c8];
        }
        int brow = tid >> 2, c8 = (tid & 3) * 8;  // B: 64*4 = 256 uint4
        br = (c8 < cur) ? *(const uint4*)&Xb[(size_t)brow * L_ + k0 + c8]
                        : make_uint4(0u, 0u, 0u, 0u);
    };
    auto stage = [&]() {
        if (tid < 192) {
            int row = tid >> 2, c8 = (tid & 3) * 8;
            *(uint4*)&Al[row * 40 + c8] = ar;
        }
        int brow = tid >> 2, c8 = (tid & 3) * 8;
        *(uint4*)&Bl[brow * 40 + c8] = br;
    };
    auto compute = [&]() {
        bf16x8 bfr = *(const bf16x8*)&Bl[(wv * 16 + fr) * 40 + quad * 8];
#pragma unroll
        for (int j = 0; j < 3; ++j) {
            bf16x8 afr = *(const bf16x8*)&Al[(j * 16 + fr) * 40 + quad * 8];
            acc[j] = MFMA16(afr, bfr, acc[j]);
        }
    };

    fetch(0); stage();
    for (int c = 1; c < 16; ++c) {
        fetch(c);
        __syncthreads();
        compute();
        __syncthreads();
        stage();
    }
    __syncthreads();
    compute();

    __syncthreads();
#pragma unroll
    for (int j = 0; j < 3; ++j)
#pragma unroll
        for (int r = 0; r < 4; ++r)
            Cst[(j * 16 + quad * 4 + r) * 64 + wv * 16 + fr] = acc[j][r];
    __syncthreads();
    float* o = out0 + (size_t)b * P_ * N_ + nt * 64;
    for (int u = tid; u < 768; u += 256) {
        int pl = u >> 4, c4 = (u & 15) * 4;
        float4* op = (float4*)&o[(size_t)(qh * 48 + pl) * N_ + c4];
        float4 pv = *op;
        const float* cs = &Cst[pl * 64 + c4];
        pv.x += cs[0]; pv.y += cs[1]; pv.z += cs[2]; pv.w += cs[3];
        *op = pv;
    }
}

// ------- Kernel 9: mid PV -> out1, grid (B, 8 n-tiles of 32), block 256 ----
__global__ __launch_bounds__(256) void k_mid_pv(const u16* __restrict__ XSB,
                                                const float* __restrict__ WM_g,
                                                float* __restrict__ out1) {
    int b = blockIdx.x, nt = blockIdx.y, tid = threadIdx.x;
    int nl = tid & 31, ks = tid >> 5;   // 8 k-slices of 61
    const u16* Xs = XSB + (size_t)b * L_ * N_ + nt * 32;
    const float* WM = WM_g + (size_t)b * MID_ * L_;
    __shared__ float wl[7 * L_];
    __shared__ float part[8][7][33];
    for (int idx = tid; idx < 7 * L_; idx += 256) wl[idx] = WM[idx];
    __syncthreads();
    float acc[7] = {};
    int kbeg = ks * 61, kend = kbeg + 61;
    for (int k = kbeg; k < kend; ++k) {
        float xv = bf2f(Xs[(size_t)k * N_ + nl]);
#pragma unroll
        for (int q = 0; q < 7; ++q) acc[q] += wl[q * L_ + k] * xv;
    }
#pragma unroll
    for (int q = 0; q < 7; ++q) part[ks][q][nl] = acc[q];
    __syncthreads();
    if (ks == 0) {
#pragma unroll
        for (int q = 0; q < 7; ++q) {
            float v = 0.f;
#pragma unroll
            for (int s = 0; s < 8; ++s) v += part[s][q][nl];
            out1[((size_t)b * MID_ + q) * N_ + nt * 32 + nl] = v;
        }
    }
}

extern "C" void kernel_launch(void* const* d_in, const int* in_sizes, int n_in,
                              void* d_out, int out_size, void* d_ws, size_t ws_size,
                              hipStream_t stream) {
    (void)in_sizes; (void)n_in; (void)out_size; (void)ws_size;
    const float* X  = (const float*)d_in[0];
    const float* T  = (const float*)d_in[1];
    const float* Wt = (const float*)d_in[2];
    const float* bt = (const float*)d_in[3];
    const float* w0 = (const float*)d_in[4];
    const float* b0 = (const float*)d_in[5];
    const float* Wp = (const float*)d_in[6];
    const float* Bp = (const float*)d_in[7];
    float* out = (float*)d_out;
    char* w8 = (char*)d_ws;
    float* out1 = out + (size_t)B_ * P_ * N_;

    u16*   XSB  = (u16*)(w8 + OFF_XSB);
    u16*   XST  = (u16*)(w8 + OFF_XST);
    u16*   TRT  = (u16*)(w8 + OFF_TRT);
    float* ET   = (float*)(w8 + OFF_ET);
    float* EN   = (float*)(w8 + OFF_EN);
    float* WSE  = (float*)(w8 + OFF_WSE);
    u16*   WSEB = (u16*)(w8 + OFF_WSEB);
    float* WM   = (float*)(w8 + OFF_WM);
    float* PART = (float*)(w8 + OFF_PART);

    hipLaunchKernelGGL(k_trend, dim3(B_, 16), dim3(256), 0, stream, X, XSB, XST, TRT);
    hipLaunchKernelGGL(k_embed, dim3((B_ * (L_ + P_) * D_) / 256), dim3(256), 0, stream,
                       T, w0, b0, Wp, Bp, ET, EN);
    hipLaunchKernelGGL(k_trend_gemm, dim3(N_, 2), dim3(256), 0, stream, Wt, TRT, PART);
    hipLaunchKernelGGL(k_reduce_trend, dim3(8, 96), dim3(256), 0, stream, PART, bt, out);
    hipLaunchKernelGGL(k_season_scores, dim3(B_, 8), dim3(256), 0, stream, EN, ET, WSE);
    hipLaunchKernelGGL(k_softmax_se, dim3(B_ * P_), dim3(64), 0, stream, WSE, WSEB);
    hipLaunchKernelGGL(k_mid_scores, dim3(B_, 8), dim3(256), 0, stream, ET, WM);
    hipLaunchKernelGGL(k_softmax_mid, dim3(B_ * MID_), dim3(64), 0, stream, WM);
    hipLaunchKernelGGL(k_season_pv, dim3(B_, 4, 2), dim3(256), 0, stream, WSEB, XST, out);
    hipLaunchKernelGGL(k_mid_pv, dim3(B_, 8), dim3(256), 0, stream, XSB, WM, out1);
}